// Round 1
// 115.445 us; speedup vs baseline: 1.1852x; 1.1852x over previous
//
#include <hip/hip_runtime.h>
#include <hip/hip_bf16.h>

#define B_ 4
#define S_ 512
#define E_ 512
#define U_ 256

// 2*log2(e): folded so tanh args feed exp2 directly: exp(2x) = exp2(KC*x)
#define KC 2.885390081777927f

#if __has_builtin(__builtin_amdgcn_exp2f)
#define EXP2F(x) __builtin_amdgcn_exp2f(x)
#else
#define EXP2F(x) __exp2f(x)
#endif
#if __has_builtin(__builtin_amdgcn_rcpf)
#define RCPF(x) __builtin_amdgcn_rcpf(x)
#else
#define RCPF(x) (1.0f / (x))
#endif

typedef __attribute__((ext_vector_type(8))) short bf16x8;
typedef __attribute__((ext_vector_type(4))) float f32x4;

__device__ __forceinline__ unsigned short bf16rn(float x) {
    unsigned int u = __float_as_uint(x);
    u = (u + 0x7FFFu + ((u >> 16) & 1u)) >> 16;   // RNE
    return (unsigned short)u;
}
// truncation split: x = hi + lo (lo exact in fp32); dropped lo*lo term ~2^-16
__device__ __forceinline__ void splitT(float x, short* hi, short* lo) {
    const unsigned u = __float_as_uint(x);
    *hi = (short)(u >> 16);
    const float hf = __uint_as_float(u & 0xFFFF0000u);
    *lo = (short)(__float_as_uint(x - hf) >> 16);
}

// ---------------------------------------------------------------------------
// Kernel 1 (512 blocks x 256 thr) — pre-GEMMs only (cast moved to scores).
//  block <-> (z, ngg 0..7 = 32-u slab, mq 0..31). 4 waves convert the W slab
//  (coalesced) into LDS B-frag hi/lo, then each wave computes one 16-row
//  m-tile (16r x 32u) with 3-MFMA hi/lo.
//  NEW: epilogue applies exp2 so the scores kernel needs NO transcendental
//  per element: exp2(KC*(q+k)) = exp2(KC*q)*exp2(KC*k).
//    z==0: ekS[b][u][j] = exp2(KC * (h1[b,j,:] @ w1[:,u]))      (j contiguous)
//    z==1: eqS[b][i][u] = exp2(KC * (h2[b,i,:] @ w2[:,u] + b1[u]))
// ---------------------------------------------------------------------------
__global__ __launch_bounds__(256) void prep_gemm(
    const float* __restrict__ h1, const float* __restrict__ h2,
    const float* __restrict__ w, const float* __restrict__ b1,
    float* __restrict__ ekS, float* __restrict__ eqS)
{
    __shared__ unsigned short WhiL[2][16][64][8];   // [nt][kc][lane][j] 32 KB
    __shared__ unsigned short WloL[2][16][64][8];   // 32 KB

    const int tid = threadIdx.x;
    const int bid = blockIdx.x;

    const int z = bid >> 8, ngg = (bid >> 5) & 7, mq = bid & 31;

    // ---- W slab conversion (coalesced rows of 32 u) ----
    const int r8 = tid >> 5, ul = tid & 31;
    const int ntc = ul >> 4, l16c = ul & 15;
    const float* __restrict__ Wp = w + (size_t)z * E_ * U_ + ngg * 32 + ul;
#pragma unroll 4
    for (int it = 0; it < 64; ++it) {
        const int k = it * 8 + r8;
        short h, l;
        splitT(Wp[(size_t)k * U_] * KC, &h, &l);
        const int kc = k >> 5, quad = (k >> 3) & 3, jj = k & 7;
        WhiL[ntc][kc][quad * 16 + l16c][jj] = (unsigned short)h;
        WloL[ntc][kc][quad * 16 + l16c][jj] = (unsigned short)l;
    }
    __syncthreads();

    // ---- MFMA main loop: one 16-row m-tile per wave ----
    const int wv = tid >> 6, lane = tid & 63;
    const int quad = lane >> 4, l16 = lane & 15;
    const int m0 = (mq * 4 + wv) * 16;
    const float* __restrict__ Arow = (z ? h2 : h1) + (size_t)(m0 + l16) * E_;

    f32x4 acc[2];
    acc[0] = (f32x4){0.f, 0.f, 0.f, 0.f};
    acc[1] = (f32x4){0.f, 0.f, 0.f, 0.f};

    for (int kc = 0; kc < 16; ++kc) {
        const int kb = kc * 32 + quad * 8;
        const float4 x0 = *(const float4*)&Arow[kb];
        const float4 x1 = *(const float4*)&Arow[kb + 4];
        const float xs[8] = {x0.x, x0.y, x0.z, x0.w, x1.x, x1.y, x1.z, x1.w};
        bf16x8 ah, al;
#pragma unroll
        for (int j = 0; j < 8; ++j) {
            short h, l; splitT(xs[j], &h, &l);
            ah[j] = h; al[j] = l;
        }
#pragma unroll
        for (int nt = 0; nt < 2; ++nt) {
            const bf16x8 bh = *(const bf16x8*)&WhiL[nt][kc][lane][0];
            const bf16x8 bl = *(const bf16x8*)&WloL[nt][kc][lane][0];
            acc[nt] = __builtin_amdgcn_mfma_f32_16x16x32_bf16(ah, bh, acc[nt], 0, 0, 0);
            acc[nt] = __builtin_amdgcn_mfma_f32_16x16x32_bf16(ah, bl, acc[nt], 0, 0, 0);
            acc[nt] = __builtin_amdgcn_mfma_f32_16x16x32_bf16(al, bh, acc[nt], 0, 0, 0);
        }
    }

    if (z == 0) {
        const int b = m0 >> 9;
        const int j0 = (m0 & (S_ - 1)) + quad * 4;       // C/D row = j
#pragma unroll
        for (int nt = 0; nt < 2; ++nt) {
            const int u = (ngg * 2 + nt) * 16 + l16;     // C/D col = u
            *(float4*)&ekS[((size_t)b * U_ + u) * S_ + j0] =
                make_float4(EXP2F(acc[nt][0]), EXP2F(acc[nt][1]),
                            EXP2F(acc[nt][2]), EXP2F(acc[nt][3]));
        }
    } else {
        const int row = m0 + quad * 4;
#pragma unroll
        for (int nt = 0; nt < 2; ++nt) {
            const int u = (ngg * 2 + nt) * 16 + l16;
            const float bias = KC * b1[u];
#pragma unroll
            for (int r = 0; r < 4; ++r)
                eqS[(size_t)(row + r) * U_ + u] = EXP2F(acc[nt][r] + bias);
        }
    }
}

// ---------------------------------------------------------------------------
// scores + softmax -> P packed in MFMA A-frag order (bf16).
// TI=4: 512 thr/block, thread t <-> column j = t, FOUR query rows per block.
// Blocks 0..511: scores. Blocks 512..767: h1 -> h1c bf16 cast (pure-memory
// work co-scheduled with the VALU-bound score blocks; 3 blocks/CU resident).
// NEW math: G = 1 + exp(2x) computed as fma(eq, ek, 1.0) — the 268M inner
// exp2's are gone (factored into prep's 1M-element epilogue).
// a = sum_u v_u/G_u via pairwise-product tree, 1 rcp per 4 u.
// score = c - 2a (c, b2 cancel) -> p ~ exp2(-a*KC); |a*KC| <= ~52 so no
// max-shift needed.
// ---------------------------------------------------------------------------
__device__ __forceinline__ float quadG(float G1, float G2, float G3, float G4,
                                       float4 vq, float acc) {
    const float P12 = G1 * G2, P34 = G3 * G4;
    const float n12 = fmaf(vq.y, G1, vq.x * G2);
    const float n34 = fmaf(vq.w, G3, vq.z * G4);
    const float num = fmaf(n34, P12, n12 * P34);
    return fmaf(num, RCPF(P12 * P34), acc);
}

__global__ __launch_bounds__(512) void scores_kernel(
    const float* __restrict__ ekS, const float* __restrict__ eqS,
    const float* __restrict__ v, unsigned short* __restrict__ Pp,
    const float* __restrict__ h1, bf16x8* __restrict__ h1c)
{
    __shared__ float ssm[8][4];
    const int bid = blockIdx.x;
    const int t = threadIdx.x;          // j = t for score blocks

    if (bid >= 512) {
        // ---- h1 -> bf16 B-frag cast for pv ----
        const int s = (bid - 512) * 512 + t;
        const int lane = s & 63, kc = (s >> 6) & 15, et = (s >> 10) & 31, b = s >> 15;
        const int quad = lane >> 4, l16 = lane & 15;
        const float* __restrict__ src =
            h1 + ((size_t)b * S_ + kc * 32 + quad * 8) * E_ + et * 16 + l16;
        bf16x8 c;
#pragma unroll
        for (int j = 0; j < 8; ++j)
            c[j] = (short)bf16rn(src[(size_t)j * E_]);
        h1c[s] = c;
        return;
    }

    const int b = bid & 3;
    const int i0 = (bid >> 2) * 4;
    const int wv = t >> 6;

    const float4* __restrict__ q0v = (const float4*)(eqS + ((size_t)b * S_ + i0) * U_);
    const float4* __restrict__ q1v = q0v + (U_ / 4);
    const float4* __restrict__ q2v = q0v + 2 * (U_ / 4);
    const float4* __restrict__ q3v = q0v + 3 * (U_ / 4);
    const float4* __restrict__ vv4 = (const float4*)v;
    const float* __restrict__ kb = ekS + (size_t)b * U_ * S_ + t;

    float a0 = 0.f, a1 = 0.f, a2 = 0.f, a3 = 0.f;
#pragma unroll 4
    for (int ub = 0; ub < U_ / 4; ++ub) {
        const float4 vq = vv4[ub];                     // uniform -> SGPR
        const float e0 = kb[(size_t)(ub * 4 + 0) * S_];
        const float e1 = kb[(size_t)(ub * 4 + 1) * S_];
        const float e2 = kb[(size_t)(ub * 4 + 2) * S_];
        const float e3 = kb[(size_t)(ub * 4 + 3) * S_];
        const float4 q0 = q0v[ub], q1 = q1v[ub], q2 = q2v[ub], q3 = q3v[ub];
        a0 = quadG(fmaf(q0.x, e0, 1.f), fmaf(q0.y, e1, 1.f),
                   fmaf(q0.z, e2, 1.f), fmaf(q0.w, e3, 1.f), vq, a0);
        a1 = quadG(fmaf(q1.x, e0, 1.f), fmaf(q1.y, e1, 1.f),
                   fmaf(q1.z, e2, 1.f), fmaf(q1.w, e3, 1.f), vq, a1);
        a2 = quadG(fmaf(q2.x, e0, 1.f), fmaf(q2.y, e1, 1.f),
                   fmaf(q2.z, e2, 1.f), fmaf(q2.w, e3, 1.f), vq, a2);
        a3 = quadG(fmaf(q3.x, e0, 1.f), fmaf(q3.y, e1, 1.f),
                   fmaf(q3.z, e2, 1.f), fmaf(q3.w, e3, 1.f), vq, a3);
    }

    const float p0 = EXP2F(-a0 * KC);
    const float p1 = EXP2F(-a1 * KC);
    const float p2 = EXP2F(-a2 * KC);
    const float p3 = EXP2F(-a3 * KC);
    float s0 = p0, s1 = p1, s2 = p2, s3 = p3;
#pragma unroll
    for (int off = 1; off < 64; off <<= 1) {
        s0 += __shfl_xor(s0, off, 64);
        s1 += __shfl_xor(s1, off, 64);
        s2 += __shfl_xor(s2, off, 64);
        s3 += __shfl_xor(s3, off, 64);
    }
    if ((t & 63) == 0) {
        ssm[wv][0] = s0; ssm[wv][1] = s1; ssm[wv][2] = s2; ssm[wv][3] = s3;
    }
    __syncthreads();
    s0 = ssm[0][0]; s1 = ssm[0][1]; s2 = ssm[0][2]; s3 = ssm[0][3];
#pragma unroll
    for (int k = 1; k < 8; ++k) {
        s0 += ssm[k][0]; s1 += ssm[k][1]; s2 += ssm[k][2]; s3 += ssm[k][3];
    }
    const float r0 = RCPF(s0), r1 = RCPF(s1), r2 = RCPF(s2), r3 = RCPF(s3);

    // pack into A-frag order: slot = (it*16 + j/32)*64 + quad(j)*16 + (i&15),
    // halfword j&7. i0 = 4*(bid>>2) -> rows stay inside one 16-block.
    const int itile = i0 >> 4;
    const int base = (itile * 16 + (t >> 5)) * 64 + (((t >> 3) & 3) << 4);
    unsigned short* __restrict__ pb = Pp + (size_t)b * S_ * S_;
    const int io = i0 & 15, jo = t & 7;
    pb[((base + io + 0) << 3) + jo] = bf16rn(p0 * r0);
    pb[((base + io + 1) << 3) + jo] = bf16rn(p1 * r1);
    pb[((base + io + 2) << 3) + jo] = bf16rn(p2 * r2);
    pb[((base + io + 3) << 3) + jo] = bf16rn(p3 * r3);
}

// ---------------------------------------------------------------------------
// pv: out[b] = P[b] @ h1[b]; A-frags pre-packed by scores, B-frags (h1c)
// by the cast blocks in scores. Wave-task (b, it 0..31, eg 0..15): 16 i x 32 e.
// grid 512x256 = 2048 wave-tasks = 2 waves/SIMD (was 1 — latency-exposed).
// ---------------------------------------------------------------------------
__global__ __launch_bounds__(256) void pv_gemm(
    const unsigned short* __restrict__ Pp, const bf16x8* __restrict__ h1c,
    float* __restrict__ out)
{
    const int tid = threadIdx.x;
    const int wv = tid >> 6, lane = tid & 63;
    const int quad = lane >> 4, l16 = lane & 15;
    const int wt = blockIdx.x * 4 + wv;          // 0..2047
    const int b = wt >> 9, rem = wt & 511;
    const int it = rem >> 4, eg = rem & 15;

    const bf16x8* __restrict__ Ab =
        (const bf16x8*)(Pp + (size_t)b * S_ * S_) + (it * 16) * 64 + lane;
    const bf16x8* __restrict__ Bb =
        h1c + ((b * 32 + eg * 2) * 16) * 64 + lane;

    f32x4 acc[2];
    acc[0] = (f32x4){0.f, 0.f, 0.f, 0.f};
    acc[1] = (f32x4){0.f, 0.f, 0.f, 0.f};

    for (int kc = 0; kc < 16; ++kc) {
        const bf16x8 a8 = Ab[kc * 64];
#pragma unroll
        for (int n = 0; n < 2; ++n) {
            const bf16x8 b8 = Bb[(n * 16 + kc) * 64];
            acc[n] = __builtin_amdgcn_mfma_f32_16x16x32_bf16(a8, b8, acc[n], 0, 0, 0);
        }
    }

    const int i = it * 16 + quad * 4;
#pragma unroll
    for (int n = 0; n < 2; ++n) {
        const int e = (eg * 2 + n) * 16 + l16;
        float* __restrict__ ob = out + ((size_t)b * S_ + i) * E_ + e;
#pragma unroll
        for (int r = 0; r < 4; ++r)
            ob[(size_t)r * E_] = acc[n][r];
    }
}

extern "C" void kernel_launch(void* const* d_in, const int* in_sizes, int n_in,
                              void* d_out, int out_size, void* d_ws, size_t ws_size,
                              hipStream_t stream) {
    const float* h1 = (const float*)d_in[0];
    const float* h2 = (const float*)d_in[1];
    const float* w  = (const float*)d_in[2];
    const float* b1 = (const float*)d_in[3];
    const float* v  = (const float*)d_in[4];
    // d_in[5] = b2: cancels in softmax, unused.
    float* out = (float*)d_out;

    char* ws = (char*)d_ws;
    float* ekS = (float*)ws;                   ws += 2u << 20;  // 2 MB
    float* eqS = (float*)ws;                   ws += 2u << 20;  // 2 MB
    unsigned short* Pp = (unsigned short*)ws;  ws += 2u << 20;  // 2 MB
    bf16x8* h1c = (bf16x8*)ws;                                  // 2 MB

    prep_gemm<<<dim3(512), dim3(256), 0, stream>>>(h1, h2, w, b1, ekS, eqS);
    scores_kernel<<<dim3(768), dim3(512), 0, stream>>>(ekS, eqS, v, Pp, h1, h1c);
    pv_gemm<<<dim3(512), dim3(256), 0, stream>>>(Pp, h1c, out);
}

// Round 2
// 114.587 us; speedup vs baseline: 1.1940x; 1.0075x over previous
//
#include <hip/hip_runtime.h>
#include <hip/hip_bf16.h>

#define B_ 4
#define S_ 512
#define E_ 512
#define U_ 256

// 2*log2(e): folded so tanh args feed exp2 directly: exp(2x) = exp2(KC*x)
#define KC 2.885390081777927f

#if __has_builtin(__builtin_amdgcn_exp2f)
#define EXP2F(x) __builtin_amdgcn_exp2f(x)
#else
#define EXP2F(x) __exp2f(x)
#endif
#if __has_builtin(__builtin_amdgcn_rcpf)
#define RCPF(x) __builtin_amdgcn_rcpf(x)
#else
#define RCPF(x) (1.0f / (x))
#endif

typedef __attribute__((ext_vector_type(8))) short bf16x8;
typedef __attribute__((ext_vector_type(4))) float f32x4;

__device__ __forceinline__ unsigned short bf16rn(float x) {
    unsigned int u = __float_as_uint(x);
    u = (u + 0x7FFFu + ((u >> 16) & 1u)) >> 16;   // RNE
    return (unsigned short)u;
}
// truncation split: x = hi + lo (lo exact in fp32); dropped lo*lo term ~2^-16
__device__ __forceinline__ void splitT(float x, short* hi, short* lo) {
    const unsigned u = __float_as_uint(x);
    *hi = (short)(u >> 16);
    const float hf = __uint_as_float(u & 0xFFFF0000u);
    *lo = (short)(__float_as_uint(x - hf) >> 16);
}

// ---------------------------------------------------------------------------
// convert: one memory-bound pass over h1,h2.
//  blocks 0..1023  -> Af: hi/lo bf16 A-fragments of h1 (z=0) and h2 (z=1)
//    for prep's MFMA A operand. Layout [z*2+hl][mt 0..127][kc 0..15][lane].
//    Previously this split-conversion ran INSIDE prep, 8x redundantly
//    (once per u-slab block) and dominated its VALU.
//  blocks 1024..1535 -> h1c: bf16 B-fragments of h1 (k = S dim) for pv.
// ---------------------------------------------------------------------------
__global__ __launch_bounds__(256) void convert_kernel(
    const float* __restrict__ h1, const float* __restrict__ h2,
    bf16x8* __restrict__ Af, bf16x8* __restrict__ h1c)
{
    const int tid = threadIdx.x;
    const int bid = blockIdx.x;

    if (bid < 1024) {
        const int g = bid * 256 + tid;
        const int lane = g & 63, kc = (g >> 6) & 15, mt = (g >> 10) & 127, z = g >> 17;
        const int quad = lane >> 4, l16 = lane & 15;
        const float* __restrict__ src = (z ? h2 : h1)
            + ((size_t)(mt * 16 + l16)) * E_ + kc * 32 + quad * 8;
        const float4 x0 = *(const float4*)src;
        const float4 x1 = *(const float4*)(src + 4);
        const float xs[8] = {x0.x, x0.y, x0.z, x0.w, x1.x, x1.y, x1.z, x1.w};
        bf16x8 ah, al;
#pragma unroll
        for (int j = 0; j < 8; ++j) {
            short h, l; splitT(xs[j] * KC, &h, &l);
            ah[j] = h; al[j] = l;
        }
        // NOTE: A carries the KC scale now (W no longer scaled) — one scalar
        // scale on the smaller side; hi*lo cross term still ~2^-16.
        const size_t o = (((size_t)z * 2 * 128 + mt) * 16 + kc) * 64 + lane;
        Af[o] = ah;
        Af[o + (size_t)128 * 16 * 64] = al;
    } else {
        const int s = (bid - 1024) * 256 + tid;
        const int lane = s & 63, kc = (s >> 6) & 15, et = (s >> 10) & 31, b = s >> 15;
        const int quad = lane >> 4, l16 = lane & 15;
        const float* __restrict__ src =
            h1 + ((size_t)b * S_ + kc * 32 + quad * 8) * E_ + et * 16 + l16;
        bf16x8 c;
#pragma unroll
        for (int j = 0; j < 8; ++j)
            c[j] = (short)bf16rn(src[(size_t)j * E_]);
        h1c[s] = c;
    }
}

// ---------------------------------------------------------------------------
// prep (512 blocks x 256 thr): pre-GEMMs from pre-converted fragments.
//  block <-> (z, ngg 0..7 = 32-u slab, mq 0..31). 4 waves convert the W slab
//  (coalesced) into LDS B-frag hi/lo (cheap: 64 iters, done once per block),
//  then each wave computes one 16-row m-tile (16r x 32u) with 3-MFMA hi/lo,
//  A-fragments streamed from Af (coalesced 16B/lane, zero VALU).
//  Epilogue applies exp2 (rank-1 factorization of the tanh exp):
//    z==0: ek4[b][u>>2][j][u&3] = exp2(KC*(h1[b,j,:] @ w1[:,u]))
//          (interleaved so scores reads one float4 per 4-u group)
//    z==1: eqS[b][i][u]         = exp2(KC*(h2[b,i,:] @ w2[:,u] + b1[u]))
// ---------------------------------------------------------------------------
__global__ __launch_bounds__(256) void prep_gemm(
    const bf16x8* __restrict__ Af,
    const float* __restrict__ w, const float* __restrict__ b1,
    float* __restrict__ ek4, float* __restrict__ eqS)
{
    __shared__ unsigned short WhiL[2][16][64][8];   // [nt][kc][lane][j] 32 KB
    __shared__ unsigned short WloL[2][16][64][8];   // 32 KB

    const int tid = threadIdx.x;
    const int bid = blockIdx.x;
    const int z = bid >> 8, ngg = (bid >> 5) & 7, mq = bid & 31;

    // ---- W slab conversion (coalesced rows of 32 u); KC now on A side ----
    const int r8 = tid >> 5, ul = tid & 31;
    const int ntc = ul >> 4, l16c = ul & 15;
    const float* __restrict__ Wp = w + (size_t)z * E_ * U_ + ngg * 32 + ul;
#pragma unroll 4
    for (int it = 0; it < 64; ++it) {
        const int k = it * 8 + r8;
        short h, l;
        splitT(Wp[(size_t)k * U_], &h, &l);
        const int kc = k >> 5, quad = (k >> 3) & 3, jj = k & 7;
        WhiL[ntc][kc][quad * 16 + l16c][jj] = (unsigned short)h;
        WloL[ntc][kc][quad * 16 + l16c][jj] = (unsigned short)l;
    }
    __syncthreads();

    // ---- MFMA main loop: one 16-row m-tile per wave, frags preloaded ----
    const int wv = tid >> 6, lane = tid & 63;
    const int quad = lane >> 4, l16 = lane & 15;
    const int mt = mq * 4 + wv, m0 = mt * 16;
    const bf16x8* __restrict__ Ah =
        Af + (((size_t)z * 2 * 128 + mt) * 16) * 64 + lane;
    const bf16x8* __restrict__ Al = Ah + (size_t)128 * 16 * 64;

    f32x4 acc[2];
    acc[0] = (f32x4){0.f, 0.f, 0.f, 0.f};
    acc[1] = (f32x4){0.f, 0.f, 0.f, 0.f};

    for (int kc = 0; kc < 16; ++kc) {
        const bf16x8 ah = Ah[kc * 64];
        const bf16x8 al = Al[kc * 64];
#pragma unroll
        for (int nt = 0; nt < 2; ++nt) {
            const bf16x8 bh = *(const bf16x8*)&WhiL[nt][kc][lane][0];
            const bf16x8 bl = *(const bf16x8*)&WloL[nt][kc][lane][0];
            acc[nt] = __builtin_amdgcn_mfma_f32_16x16x32_bf16(ah, bh, acc[nt], 0, 0, 0);
            acc[nt] = __builtin_amdgcn_mfma_f32_16x16x32_bf16(ah, bl, acc[nt], 0, 0, 0);
            acc[nt] = __builtin_amdgcn_mfma_f32_16x16x32_bf16(al, bh, acc[nt], 0, 0, 0);
        }
    }

    if (z == 0) {
        const int b = m0 >> 9;
        const int j0 = (m0 & (S_ - 1)) + quad * 4;       // C/D row = j
#pragma unroll
        for (int nt = 0; nt < 2; ++nt) {
            const int u = (ngg * 2 + nt) * 16 + l16;     // C/D col = u
            float* __restrict__ dst =
                ek4 + ((size_t)b * 64 + (u >> 2)) * 2048 + (u & 3);
#pragma unroll
            for (int r = 0; r < 4; ++r)
                dst[(size_t)(j0 + r) * 4] = EXP2F(acc[nt][r]);
        }
    } else {
        const int row = m0 + quad * 4;
#pragma unroll
        for (int nt = 0; nt < 2; ++nt) {
            const int u = (ngg * 2 + nt) * 16 + l16;
            const float bias = KC * b1[u];
#pragma unroll
            for (int r = 0; r < 4; ++r)
                eqS[(size_t)(row + r) * U_ + u] = EXP2F(acc[nt][r] + bias);
        }
    }
}

// ---------------------------------------------------------------------------
// scores + softmax -> P packed in MFMA A-frag order (bf16).
// TI=4: 512 thr/block, thread t <-> column j = t, FOUR query rows per block.
// grid (128,4) = 512 blocks x 8 waves. Inner loop per 4-u group is now ONE
// coalesced dwordx4 k-load (ek4 interleaved layout) + 52 VALU + 4 rcp.
// G = 1 + exp(2x) = fma(eq, ek, 1.0) — no transcendental per element.
// a = sum_u v_u/G_u via pairwise-product tree, 1 rcp per 4 u.
// score = c - 2a (c, b2 cancel) -> p ~ exp2(-a*KC); |a*KC| <= ~52.
// ---------------------------------------------------------------------------
__device__ __forceinline__ float quadG(float G1, float G2, float G3, float G4,
                                       float4 vq, float acc) {
    const float P12 = G1 * G2, P34 = G3 * G4;
    const float n12 = fmaf(vq.y, G1, vq.x * G2);
    const float n34 = fmaf(vq.w, G3, vq.z * G4);
    const float num = fmaf(n34, P12, n12 * P34);
    return fmaf(num, RCPF(P12 * P34), acc);
}

__global__ __launch_bounds__(512) void scores_kernel(
    const float* __restrict__ ek4, const float* __restrict__ eqS,
    const float* __restrict__ v, unsigned short* __restrict__ Pp)
{
    __shared__ float ssm[8][4];
    const int i0 = blockIdx.x * 4;
    const int b = blockIdx.y;
    const int t = threadIdx.x;          // j = t
    const int wv = t >> 6;

    const float4* __restrict__ q0v = (const float4*)(eqS + ((size_t)b * S_ + i0) * U_);
    const float4* __restrict__ q1v = q0v + (U_ / 4);
    const float4* __restrict__ q2v = q0v + 2 * (U_ / 4);
    const float4* __restrict__ q3v = q0v + 3 * (U_ / 4);
    const float4* __restrict__ vv4 = (const float4*)v;
    const float4* __restrict__ kbb = (const float4*)ek4 + (size_t)b * 64 * 512 + t;

    float a0 = 0.f, a1 = 0.f, a2 = 0.f, a3 = 0.f;
#pragma unroll 4
    for (int ub = 0; ub < U_ / 4; ++ub) {
        const float4 vq = vv4[ub];                     // uniform -> SGPR
        const float4 e = kbb[(size_t)ub * 512];        // one coalesced 16B load
        const float4 q0 = q0v[ub], q1 = q1v[ub], q2 = q2v[ub], q3 = q3v[ub];
        a0 = quadG(fmaf(q0.x, e.x, 1.f), fmaf(q0.y, e.y, 1.f),
                   fmaf(q0.z, e.z, 1.f), fmaf(q0.w, e.w, 1.f), vq, a0);
        a1 = quadG(fmaf(q1.x, e.x, 1.f), fmaf(q1.y, e.y, 1.f),
                   fmaf(q1.z, e.z, 1.f), fmaf(q1.w, e.w, 1.f), vq, a1);
        a2 = quadG(fmaf(q2.x, e.x, 1.f), fmaf(q2.y, e.y, 1.f),
                   fmaf(q2.z, e.z, 1.f), fmaf(q2.w, e.w, 1.f), vq, a2);
        a3 = quadG(fmaf(q3.x, e.x, 1.f), fmaf(q3.y, e.y, 1.f),
                   fmaf(q3.z, e.z, 1.f), fmaf(q3.w, e.w, 1.f), vq, a3);
    }

    const float p0 = EXP2F(-a0 * KC);
    const float p1 = EXP2F(-a1 * KC);
    const float p2 = EXP2F(-a2 * KC);
    const float p3 = EXP2F(-a3 * KC);
    float s0 = p0, s1 = p1, s2 = p2, s3 = p3;
#pragma unroll
    for (int off = 1; off < 64; off <<= 1) {
        s0 += __shfl_xor(s0, off, 64);
        s1 += __shfl_xor(s1, off, 64);
        s2 += __shfl_xor(s2, off, 64);
        s3 += __shfl_xor(s3, off, 64);
    }
    if ((t & 63) == 0) {
        ssm[wv][0] = s0; ssm[wv][1] = s1; ssm[wv][2] = s2; ssm[wv][3] = s3;
    }
    __syncthreads();
    s0 = ssm[0][0]; s1 = ssm[0][1]; s2 = ssm[0][2]; s3 = ssm[0][3];
#pragma unroll
    for (int k = 1; k < 8; ++k) {
        s0 += ssm[k][0]; s1 += ssm[k][1]; s2 += ssm[k][2]; s3 += ssm[k][3];
    }
    const float r0 = RCPF(s0), r1 = RCPF(s1), r2 = RCPF(s2), r3 = RCPF(s3);

    // pack into A-frag order: slot = (it*16 + j/32)*64 + quad(j)*16 + (i&15),
    // halfword j&7. i0 = 4*blockIdx.x -> rows stay inside one 16-block.
    const int itile = i0 >> 4;
    const int base = (itile * 16 + (t >> 5)) * 64 + (((t >> 3) & 3) << 4);
    unsigned short* __restrict__ pb = Pp + (size_t)b * S_ * S_;
    const int io = i0 & 15, jo = t & 7;
    pb[((base + io + 0) << 3) + jo] = bf16rn(p0 * r0);
    pb[((base + io + 1) << 3) + jo] = bf16rn(p1 * r1);
    pb[((base + io + 2) << 3) + jo] = bf16rn(p2 * r2);
    pb[((base + io + 3) << 3) + jo] = bf16rn(p3 * r3);
}

// ---------------------------------------------------------------------------
// pv: out[b] = P[b] @ h1[b]; A-frags pre-packed by scores, B-frags (h1c)
// by convert. Wave-task (b, it 0..31, eg 0..15): 16 i x 32 e.
// grid 512x256 = 2048 wave-tasks = 2 waves/SIMD.
// ---------------------------------------------------------------------------
__global__ __launch_bounds__(256) void pv_gemm(
    const unsigned short* __restrict__ Pp, const bf16x8* __restrict__ h1c,
    float* __restrict__ out)
{
    const int tid = threadIdx.x;
    const int wv = tid >> 6, lane = tid & 63;
    const int quad = lane >> 4, l16 = lane & 15;
    const int wt = blockIdx.x * 4 + wv;          // 0..2047
    const int b = wt >> 9, rem = wt & 511;
    const int it = rem >> 4, eg = rem & 15;

    const bf16x8* __restrict__ Ab =
        (const bf16x8*)(Pp + (size_t)b * S_ * S_) + (it * 16) * 64 + lane;
    const bf16x8* __restrict__ Bb =
        h1c + ((b * 32 + eg * 2) * 16) * 64 + lane;

    f32x4 acc[2];
    acc[0] = (f32x4){0.f, 0.f, 0.f, 0.f};
    acc[1] = (f32x4){0.f, 0.f, 0.f, 0.f};

    for (int kc = 0; kc < 16; ++kc) {
        const bf16x8 a8 = Ab[kc * 64];
#pragma unroll
        for (int n = 0; n < 2; ++n) {
            const bf16x8 b8 = Bb[(n * 16 + kc) * 64];
            acc[n] = __builtin_amdgcn_mfma_f32_16x16x32_bf16(a8, b8, acc[n], 0, 0, 0);
        }
    }

    const int i = it * 16 + quad * 4;
#pragma unroll
    for (int n = 0; n < 2; ++n) {
        const int e = (eg * 2 + n) * 16 + l16;
        float* __restrict__ ob = out + ((size_t)b * S_ + i) * E_ + e;
#pragma unroll
        for (int r = 0; r < 4; ++r)
            ob[(size_t)r * E_] = acc[n][r];
    }
}

extern "C" void kernel_launch(void* const* d_in, const int* in_sizes, int n_in,
                              void* d_out, int out_size, void* d_ws, size_t ws_size,
                              hipStream_t stream) {
    const float* h1 = (const float*)d_in[0];
    const float* h2 = (const float*)d_in[1];
    const float* w  = (const float*)d_in[2];
    const float* b1 = (const float*)d_in[3];
    const float* v  = (const float*)d_in[4];
    // d_in[5] = b2: cancels in softmax, unused.
    float* out = (float*)d_out;

    char* ws = (char*)d_ws;
    float* ek4 = (float*)ws;                   ws += 2u << 20;  // 2 MB
    float* eqS = (float*)ws;                   ws += 2u << 20;  // 2 MB
    unsigned short* Pp = (unsigned short*)ws;  ws += 2u << 20;  // 2 MB
    bf16x8* h1c = (bf16x8*)ws;                 ws += 2u << 20;  // 2 MB
    bf16x8* Af  = (bf16x8*)ws;                                  // 8 MB

    convert_kernel<<<dim3(1536), dim3(256), 0, stream>>>(h1, h2, Af, h1c);
    prep_gemm<<<dim3(512), dim3(256), 0, stream>>>(Af, w, b1, ek4, eqS);
    scores_kernel<<<dim3(S_ / 4, B_), dim3(512), 0, stream>>>(ek4, eqS, v, Pp);
    pv_gemm<<<dim3(512), dim3(256), 0, stream>>>(Pp, h1c, out);
}